// Round 11
// baseline (42.890 us; speedup 1.0000x reference)
//
#include <hip/hip_runtime.h>
#include <hip/hip_bf16.h>

#define L2E 1.4426950408889634f
#define LN2 0.6931471805599453f

#if defined(__has_builtin)
#if __has_builtin(__builtin_amdgcn_exp2f)
#define EXP2(x) __builtin_amdgcn_exp2f(x)
#else
#define EXP2(x) exp2f(x)
#endif
#if __has_builtin(__builtin_amdgcn_logf)
#define LOG2(x) __builtin_amdgcn_logf(x)
#else
#define LOG2(x) __log2f(x)
#endif
#else
#define EXP2(x) exp2f(x)
#define LOG2(x) __log2f(x)
#endif

typedef __attribute__((ext_vector_type(8))) short bf16x8;
typedef __attribute__((ext_vector_type(4))) float f32x4;
typedef __attribute__((ext_vector_type(2))) float f32x2;

__device__ __forceinline__ void gld_lds16(const void* g, void* l) {
  __builtin_amdgcn_global_load_lds(
      (const __attribute__((address_space(1))) void*)g,
      (__attribute__((address_space(3))) void*)l, 16, 0, 0);
}

__device__ __forceinline__ unsigned bf16rne(float f) {
  unsigned u = __float_as_uint(f);
  return (u + 0x7fffu + ((u >> 16) & 1u)) >> 16;
}

// Kernel A: L2-normalize embedding table -> packed bf16 (2 per uint32).
// float4 loads, 2 rows per wave. At HBM floor (~6.1us for 38.4MB).
__global__ __launch_bounds__(256) void knrm_norm(const float* __restrict__ emb,
                                                 unsigned* __restrict__ embN) {
  const int t = threadIdx.x;
  const int l = t & 31;
  const int sub = (t >> 5) & 1;
  int wv = blockIdx.x * 4 + (t >> 6);
  const int nW = gridDim.x * 4;
  for (int rp = wv; rp < 25000; rp += nW) {
    int r = rp * 2 + sub;
    float4 v = *(const float4*)(emb + (size_t)r * 128 + l * 4);
    float ss = v.x * v.x + v.y * v.y + v.z * v.z + v.w * v.w;
#pragma unroll
    for (int m = 1; m < 32; m <<= 1) ss += __shfl_xor(ss, m, 64);  // within 32-lane half
    float sc = 1.0f / fmaxf(sqrtf(ss), 1e-12f);
    uint2 o;
    o.x = bf16rne(v.x * sc) | (bf16rne(v.y * sc) << 16);
    o.y = bf16rne(v.z * sc) | (bf16rne(v.w * sc) << 16);
    *(uint2*)(embN + (size_t)r * 64 + l * 2) = o;
  }
}

// Kernel B: per batch item, 256 threads (4 waves), WAVES FULLY DECOUPLED:
// each wave owns a private 3-deep ring of 16-row doc tiles (stages all 16
// rows itself, 4x global_load_lds per stage; the 4 waves' duplicate gathers
// hit L1/L2). ZERO barriers in the main loop — per-wave s_waitcnt vmcnt(4)
// only (2-stage private lookahead). One mfma_f32_16x16x32_bf16 tile per
// stage; 20 Gaussian kernels via middle-out geometric chain in packed f32.
// kmbuf overlays each wave's own dead ring after the loop.
__global__ __launch_bounds__(256, 4) void knrm_main(
    const int* __restrict__ query, const int* __restrict__ doc,
    const unsigned* __restrict__ embN,
    const float* __restrict__ W1, const float* __restrict__ b1,
    const float* __restrict__ W2, const float* __restrict__ b2,
    const float* __restrict__ W3, const float* __restrict__ b3,
    float* __restrict__ out) {
  __shared__ __align__(16) char dbuf[4][3][16 * 256];  // per-wave 3-deep rings
  __shared__ int dtok[256];
  __shared__ float km2[4][21];
  __shared__ float kmv[21];
  __shared__ float x1[10];
  __shared__ float x2[5];

  const int b = blockIdx.x;
  const int tid = threadIdx.x;
  const int w = tid >> 6;  // wave = q-strip
  const int lane = tid & 63;
  const int lo = lane & 15, hi = lane >> 4;
  const char* embB = (const char*)embN;  // 256 B per vocab row (128 bf16)
  char* ring = dbuf[w][0];               // this wave's private 12KB

  // ---- Q fragments straight from global (B-operand: col=lo=q, k=8*hi+e).
  const int myq = query[b * 64 + w * 16 + lo];
  bf16x8 bq[4];
#pragma unroll
  for (int kk = 0; kk < 4; ++kk)
    bq[kk] = *(const bf16x8*)(embB + (size_t)myq * 256 + kk * 64 + hi * 16);

  dtok[tid] = doc[b * 256 + tid];
  __syncthreads();  // barrier #1: dtok visible (also drains bq, harmless)

  // ---- staging: per gld g (g=0..3), lane covers row g*4+(lane>>4) of the
  // 16-row tile, 16B slot lane&15. LDS dest linear (wave-uniform base +
  // lane*16); read side uses phys_slot = logical ^ (row&7), so the SOURCE
  // slot is pre-swizzled with the same XOR.
  const int grow = lane >> 4;                   // row-within-quad
  const int gslot0 = lane & 15;                 // logical slot
  // prologue: stages 0,1 into ring slots 0,1 (4 glds each)
#pragma unroll
  for (int s = 0; s < 2; ++s) {
#pragma unroll
    for (int g = 0; g < 4; ++g) {
      int r = g * 4 + grow;
      int tok = dtok[s * 16 + r];
      gld_lds16(embB + (size_t)tok * 256 + (size_t)(gslot0 ^ (r & 7)) * 16,
                ring + s * 4096 + g * 1024);
    }
  }

  f32x2 acc20[20];  // packed accumulators: .x sums elems (e=0,2), .y (e=1,3)
#pragma unroll
  for (int j = 0; j < 20; ++j) acc20[j] = (f32x2){0.0f, 0.0f};

  // One stage: wait own stage-s DMAs (4 left in flight = stage s+1's),
  // prefetch stage s+2 into the ring slot freed by stage s-1 (own-wave
  // in-order reads already retired; no cross-wave hazard exists), then
  // ds_read + MFMA + chain on stage s. NO barrier.
#define STAGE(s, SLOT, PSLOT, VMLIT)                                          \
  {                                                                           \
    asm volatile("s_waitcnt vmcnt(" #VMLIT ")" ::: "memory");                 \
    if ((s) + 2 < 16) {                                                       \
      _Pragma("unroll")                                                       \
      for (int g = 0; g < 4; ++g) {                                           \
        int r = g * 4 + grow;                                                 \
        int tok = dtok[((s) + 2) * 16 + r];                                   \
        gld_lds16(embB + (size_t)tok * 256 + (size_t)(gslot0 ^ (r & 7)) * 16, \
                  ring + (PSLOT)*4096 + g * 1024);                            \
      }                                                                       \
    }                                                                         \
    const char* buf = ring + (SLOT)*4096;                                     \
    f32x4 mm = {0.0f, 0.0f, 0.0f, 0.0f};                                      \
    _Pragma("unroll")                                                         \
    for (int kk = 0; kk < 4; ++kk) {                                          \
      int slot = (kk * 4 + hi) ^ (lo & 7); /* A-op: row=lo, k=8*hi+e */       \
      bf16x8 a = *(const bf16x8*)(buf + lo * 256 + slot * 16);                \
      mm = __builtin_amdgcn_mfma_f32_16x16x32_bf16(a, bq[kk], mm, 0, 0, 0);   \
    }                                                                         \
    /* mm[e]: doc = s*16 + 4*hi + e, q = w*16 + lo.                           \
       raw_j = exp(-50v^2+100*v*mu_j), mu_j = -0.95+0.1j; middle-out chain    \
       from j=9: intermediates <= e^45.1, tails underflow only where the     \
       true value ~0. acc[j]=pk_fma(t,G,acc[j]) || t=pk_mul(t,G). */          \
    _Pragma("unroll")                                                         \
    for (int p = 0; p < 2; ++p) {                                             \
      float vx = mm[p], vy = mm[p + 2];                                       \
      float a10x = vx * (10.0f * L2E), a10y = vy * (10.0f * L2E);             \
      f32x2 G = {EXP2(a10x), EXP2(a10y)};                                     \
      f32x2 Gi = {EXP2(-a10x), EXP2(-a10y)};                                  \
      f32x2 tu = {EXP2((vx * L2E) * fmaf(-50.0f, vx, -5.0f)),                 \
                  EXP2((vy * L2E) * fmaf(-50.0f, vy, -5.0f))};                \
      f32x2 td = tu;                                                          \
      asm("v_pk_add_f32 %0, %0, %1" : "+v"(acc20[9]) : "v"(tu));              \
      _Pragma("unroll")                                                       \
      for (int j = 10; j < 20; ++j) {                                         \
        asm("v_pk_fma_f32 %0, %1, %2, %0" : "+v"(acc20[j]) : "v"(tu), "v"(G)); \
        if (j < 19) asm("v_pk_mul_f32 %0, %0, %1" : "+v"(tu) : "v"(G));       \
      }                                                                       \
      _Pragma("unroll")                                                       \
      for (int j = 8; j >= 0; --j) {                                          \
        asm("v_pk_fma_f32 %0, %1, %2, %0" : "+v"(acc20[j]) : "v"(td), "v"(Gi)); \
        if (j > 0) asm("v_pk_mul_f32 %0, %0, %1" : "+v"(td) : "v"(Gi));       \
      }                                                                       \
    }                                                                         \
  }

#pragma unroll 1
  for (int s5 = 0; s5 < 5; ++s5) {
    int s = s5 * 3;
    STAGE(s, 0, 2, 4);
    STAGE(s + 1, 1, 0, 4);
    STAGE(s + 2, 2, 1, 4);
  }
  STAGE(15, 0, 2, 0);  // last stage: drain own final DMAs
#undef STAGE

  // ---- exact-match kernel via integer equality (lane covers docs 64*hi..+63;
  // padding token 0 is a zero vector -> cosine 0, never matches) ----
  int cnt = 0;
#pragma unroll 16
  for (int i = 0; i < 64; ++i) cnt += (dtok[hi * 64 + i] == myq) ? 1 : 0;
  cnt = (myq == 0) ? 0 : cnt;
  cnt += __shfl_xor(cnt, 16, 64);
  cnt += __shfl_xor(cnt, 32, 64);

  // ---- horizontal fold + reduce over hi (lanes 16,32 apart share same q) ----
  float sa[20];
#pragma unroll
  for (int j = 0; j < 20; ++j) {
    float s2 = acc20[j].x + acc20[j].y;
    s2 += __shfl_xor(s2, 16, 64);
    s2 += __shfl_xor(s2, 32, 64);
    sa[j] = s2;
  }

  // kmbuf overlays this wave's own (dead) ring: [16 q][21]
  float* kmq = (float*)ring;
  if (hi == 0) {
#pragma unroll
    for (int j = 0; j < 20; ++j) kmq[lo * 21 + j] = sa[j];
    kmq[lo * 21 + 20] = (float)cnt;
  }
  __syncthreads();  // barrier #2: all waves' kmbuf strips visible

  // ---- km[j] = sum_q log(1 + C_j*rawsum) via native log2, C_j = exp(-50 mu^2)
  const float cA = -50.0f * L2E;
  if (tid < 84) {
    int j = tid % 21, c = tid / 21;
    float Cj = 1.0f;
    if (j < 20) {
      float mu = -0.95f + 0.1f * (float)j;
      Cj = EXP2(cA * mu * mu);
    }
    float s = 0.0f;
    for (int q = 0; q < 16; ++q) {
      float raw = ((const float*)dbuf[c])[q * 21 + j];
      s += LOG2(fmaf(Cj, raw, 1.0f));
    }
    km2[c][j] = s * LN2;
  }
  __syncthreads();
  if (tid < 21)
    kmv[tid] = fmaxf(km2[0][tid] + km2[1][tid] + km2[2][tid] + km2[3][tid], 0.0f);
  __syncthreads();
  if (tid < 10) {
    float s = b1[tid];
    for (int j = 0; j < 21; ++j) s = fmaf(W1[tid * 21 + j], kmv[j], s);
    x1[tid] = fmaxf(s, 0.0f);
  }
  __syncthreads();
  if (tid < 5) {
    float s = b2[tid];
    for (int i = 0; i < 10; ++i) s = fmaf(W2[tid * 10 + i], x1[i], s);
    x2[tid] = s;
  }
  __syncthreads();
  if (tid == 0) {
    float s = b3[0];
    for (int i = 0; i < 5; ++i) s = fmaf(W3[i], x2[i], s);
    out[b] = s;
  }
}

extern "C" void kernel_launch(void* const* d_in, const int* in_sizes, int n_in,
                              void* d_out, int out_size, void* d_ws, size_t ws_size,
                              hipStream_t stream) {
  const int* query = (const int*)d_in[0];
  const int* doc = (const int*)d_in[1];
  const float* emb = (const float*)d_in[2];
  const float* W1 = (const float*)d_in[3];
  const float* b1 = (const float*)d_in[4];
  const float* W2 = (const float*)d_in[5];
  const float* b2 = (const float*)d_in[6];
  const float* W3 = (const float*)d_in[7];
  const float* b3 = (const float*)d_in[8];
  float* out = (float*)d_out;
  unsigned* embN = (unsigned*)d_ws;  // 50000*64 uints = 12.8 MB bf16 table

  hipLaunchKernelGGL(knrm_norm, dim3(1024), dim3(256), 0, stream, emb, embN);
  hipLaunchKernelGGL(knrm_main, dim3(1024), dim3(256), 0, stream, query, doc, embN,
                     W1, b1, W2, b2, W3, b3, out);
}

// Round 12
// 41.070 us; speedup vs baseline: 1.0443x; 1.0443x over previous
//
#include <hip/hip_runtime.h>
#include <hip/hip_bf16.h>

#define L2E 1.4426950408889634f
#define LN2 0.6931471805599453f

#if defined(__has_builtin)
#if __has_builtin(__builtin_amdgcn_exp2f)
#define EXP2(x) __builtin_amdgcn_exp2f(x)
#else
#define EXP2(x) exp2f(x)
#endif
#if __has_builtin(__builtin_amdgcn_logf)
#define LOG2(x) __builtin_amdgcn_logf(x)
#else
#define LOG2(x) __log2f(x)
#endif
#else
#define EXP2(x) exp2f(x)
#define LOG2(x) __log2f(x)
#endif

typedef __attribute__((ext_vector_type(8))) short bf16x8;
typedef __attribute__((ext_vector_type(4))) float f32x4;
typedef __attribute__((ext_vector_type(2))) float f32x2;

__device__ __forceinline__ void gld_lds16(const void* g, void* l) {
  __builtin_amdgcn_global_load_lds(
      (const __attribute__((address_space(1))) void*)g,
      (__attribute__((address_space(3))) void*)l, 16, 0, 0);
}

__device__ __forceinline__ unsigned bf16rne(float f) {
  unsigned u = __float_as_uint(f);
  return (u + 0x7fffu + ((u >> 16) & 1u)) >> 16;
}

// Kernel A: L2-normalize embedding table -> packed bf16 (2 per uint32).
// float4 loads, 2 rows per wave. At HBM floor (~6.1us for 38.4MB).
__global__ __launch_bounds__(256) void knrm_norm(const float* __restrict__ emb,
                                                 unsigned* __restrict__ embN) {
  const int t = threadIdx.x;
  const int l = t & 31;
  const int sub = (t >> 5) & 1;
  int wv = blockIdx.x * 4 + (t >> 6);
  const int nW = gridDim.x * 4;
  for (int rp = wv; rp < 25000; rp += nW) {
    int r = rp * 2 + sub;
    float4 v = *(const float4*)(emb + (size_t)r * 128 + l * 4);
    float ss = v.x * v.x + v.y * v.y + v.z * v.z + v.w * v.w;
#pragma unroll
    for (int m = 1; m < 32; m <<= 1) ss += __shfl_xor(ss, m, 64);  // within 32-lane half
    float sc = 1.0f / fmaxf(sqrtf(ss), 1e-12f);
    uint2 o;
    o.x = bf16rne(v.x * sc) | (bf16rne(v.y * sc) << 16);
    o.y = bf16rne(v.z * sc) | (bf16rne(v.w * sc) << 16);
    *(uint2*)(embN + (size_t)r * 64 + l * 2) = o;
  }
}

// Kernel B: per batch item, 256 threads (4 waves). Docs staged in 16-row
// sixteenths (double-buffered LDS, one global_load_lds per thread per stage).
// Wave w computes q-strip w vs the staged 16 doc rows via one
// mfma_f32_16x16x32_bf16 tile per stage. 20 Gaussian kernels via middle-out
// geometric chain in packed f32x2 with STRIDE-2 sub-chains (dependency depth
// 19 -> ~5; 8 independent streams per stage; exps hoisted ahead of chains).
// Exact-match kernel = integer token compare.
__global__ __launch_bounds__(256, 4) void knrm_main(
    const int* __restrict__ query, const int* __restrict__ doc,
    const unsigned* __restrict__ embN,
    const float* __restrict__ W1, const float* __restrict__ b1,
    const float* __restrict__ W2, const float* __restrict__ b2,
    const float* __restrict__ W3, const float* __restrict__ b3,
    float* __restrict__ out) {
  __shared__ __align__(16) char dbuf[2][16 * 256];  // 2 x 4KB doc sixteenths
  __shared__ float kmbuf[64 * 21];
  __shared__ int dtok[256];
  __shared__ float km2[4][21];
  __shared__ float kmv[21];
  __shared__ float x1[10];
  __shared__ float x2[5];

  const int b = blockIdx.x;
  const int tid = threadIdx.x;
  const int w = tid >> 6;  // wave = q-strip
  const int lane = tid & 63;
  const int lo = lane & 15, hi = lane >> 4;
  const char* embB = (const char*)embN;  // 256 B per vocab row (128 bf16)

  dtok[tid] = doc[b * 256 + tid];

  // ---- Q fragments straight from global (B-operand: col=lo=q, k=8*hi+e) ----
  const int myq = query[b * 64 + w * 16 + lo];
  bf16x8 bq[4];
#pragma unroll
  for (int kk = 0; kk < 4; ++kk)
    bq[kk] = *(const bf16x8*)(embB + (size_t)myq * 256 + kk * 64 + hi * 16);

  // ---- staging geometry: thread t owns 16B slot (t&15) of stage-row (t>>4).
  // LDS rows are 256B; slots XOR-swizzled: LDS[row][s] = G[row][s^(row&7)].
  // global_load_lds writes linearly (wave-uniform base + lane*16): wave w
  // covers rows w*4..w*4+3 == t>>4. Source slot pre-swizzled.
  const int srow = tid >> 4;                   // 0..15
  const int sslot = (tid & 15) ^ (srow & 7);   // pre-swizzled source slot
  {
    int tok = doc[b * 256 + srow];  // dtok not yet visible (no barrier yet)
    gld_lds16(embB + (size_t)tok * 256 + sslot * 16, dbuf[0] + w * 1024);
  }
  asm volatile("s_waitcnt vmcnt(0)" ::: "memory");
  __syncthreads();

  f32x2 acc20[20];  // packed accumulators: .x sums elems (e=0,2), .y (e=1,3)
#pragma unroll
  for (int j = 0; j < 20; ++j) acc20[j] = (f32x2){0.0f, 0.0f};

#pragma unroll 1
  for (int s = 0; s < 16; ++s) {
    const int cur = s & 1;
    // prefetch next sixteenth into the other buffer (overlaps compute below;
    // safe: barrier ending stage s-1 guaranteed all reads of it finished)
    if (s < 15) {
      int tok = dtok[(s + 1) * 16 + srow];
      gld_lds16(embB + (size_t)tok * 256 + sslot * 16, dbuf[cur ^ 1] + w * 1024);
    }
    // one 16x16 tile: doc rows s*16..s*16+15 vs q-strip w
    f32x4 mm = {0.0f, 0.0f, 0.0f, 0.0f};
#pragma unroll
    for (int kk = 0; kk < 4; ++kk) {
      int slot = (kk * 4 + hi) ^ (lo & 7);  // A-operand: row=lo, k=8*hi+e
      bf16x8 a = *(const bf16x8*)(dbuf[cur] + lo * 256 + slot * 16);
      mm = __builtin_amdgcn_mfma_f32_16x16x32_bf16(a, bq[kk], mm, 0, 0, 0);
    }
    // mm[e]: doc = s*16 + 4*hi + e, q = w*16 + lo
    // raw_j = exp(-50v^2 + 100*v*mu_j), mu_j = -0.95 + 0.1j.
    // Middle-out from j=9: w_k = t9*G^k up (acc[9+k]), t9*Gi^k down
    // (acc[9-k]); intermediates <= e^45.1, tails underflow only where the
    // true value ~0. STRIDE-2: two sub-chains per direction advance by G^2,
    // halving dependency depth; all 12 exps issued before any chain.
    {
      f32x2 v0 = {mm[0], mm[2]};
      f32x2 v1 = {mm[1], mm[3]};
      f32x2 a0 = v0 * (10.0f * L2E), a1 = v1 * (10.0f * L2E);
      f32x2 e90 = (v0 * L2E) * (v0 * -50.0f - 5.0f);
      f32x2 e91 = (v1 * L2E) * (v1 * -50.0f - 5.0f);
      f32x2 G0 = {EXP2(a0.x), EXP2(a0.y)};
      f32x2 Gi0 = {EXP2(-a0.x), EXP2(-a0.y)};
      f32x2 t90 = {EXP2(e90.x), EXP2(e90.y)};
      f32x2 G1 = {EXP2(a1.x), EXP2(a1.y)};
      f32x2 Gi1 = {EXP2(-a1.x), EXP2(-a1.y)};
      f32x2 t91 = {EXP2(e91.x), EXP2(e91.y)};

#define CHAIN(G, Gi, t9)                                                   \
  {                                                                        \
    f32x2 G2 = (G) * (G);                                                  \
    f32x2 Gi2 = (Gi) * (Gi);                                               \
    acc20[9] += (t9);                                                      \
    f32x2 u0 = (t9) * (G);    /* k=1,3,5,7,9 */                            \
    f32x2 u1 = (t9) * G2;     /* k=2,4,6,8,10 */                           \
    f32x2 d0 = (t9) * (Gi);   /* k=1,3,5,7,9 */                            \
    f32x2 d1 = (t9) * Gi2;    /* k=2,4,6,8 */                              \
    acc20[10] += u0;                                                       \
    acc20[11] += u1;                                                       \
    acc20[8] += d0;                                                        \
    acc20[7] += d1;                                                        \
    acc20[12] += u0 * G2; u0 *= G2;                                        \
    acc20[13] += u1 * G2; u1 *= G2;                                        \
    acc20[6] += d0 * Gi2; d0 *= Gi2;                                       \
    acc20[5] += d1 * Gi2; d1 *= Gi2;                                       \
    acc20[14] += u0 * G2; u0 *= G2;                                        \
    acc20[15] += u1 * G2; u1 *= G2;                                        \
    acc20[4] += d0 * Gi2; d0 *= Gi2;                                       \
    acc20[3] += d1 * Gi2; d1 *= Gi2;                                       \
    acc20[16] += u0 * G2; u0 *= G2;                                        \
    acc20[17] += u1 * G2; u1 *= G2;                                        \
    acc20[2] += d0 * Gi2; d0 *= Gi2;                                       \
    acc20[1] += d1 * Gi2;                                                  \
    acc20[18] += u0 * G2;                                                  \
    acc20[19] += u1 * G2;                                                  \
    acc20[0] += d0 * Gi2;                                                  \
  }
      CHAIN(G0, Gi0, t90)
      CHAIN(G1, Gi1, t91)
#undef CHAIN
    }
    asm volatile("s_waitcnt vmcnt(0)" ::: "memory");  // own prefetch drained
    __syncthreads();                                  // everyone's landed
  }

  // ---- exact-match kernel via integer equality (lane covers docs 64*hi..+63;
  // padding token 0 is a zero vector -> cosine 0, never matches) ----
  int cnt = 0;
#pragma unroll 16
  for (int i = 0; i < 64; ++i) cnt += (dtok[hi * 64 + i] == myq) ? 1 : 0;
  cnt = (myq == 0) ? 0 : cnt;
  cnt += __shfl_xor(cnt, 16, 64);
  cnt += __shfl_xor(cnt, 32, 64);

  // ---- horizontal fold + reduce over hi (lanes 16,32 apart share same q) ----
  float sa[20];
#pragma unroll
  for (int j = 0; j < 20; ++j) {
    float s2 = acc20[j].x + acc20[j].y;
    s2 += __shfl_xor(s2, 16, 64);
    s2 += __shfl_xor(s2, 32, 64);
    sa[j] = s2;
  }

  if (hi == 0) {
    int q = w * 16 + lo;
#pragma unroll
    for (int j = 0; j < 20; ++j) kmbuf[q * 21 + j] = sa[j];
    kmbuf[q * 21 + 20] = (float)cnt;
  }
  __syncthreads();

  // ---- km[j] = sum_q log(1 + C_j*rawsum) via native log2, C_j = exp(-50 mu^2)
  const float cA = -50.0f * L2E;
  if (tid < 84) {
    int j = tid % 21, c = tid / 21;
    float Cj = 1.0f;
    if (j < 20) {
      float mu = -0.95f + 0.1f * (float)j;
      Cj = EXP2(cA * mu * mu);
    }
    float s = 0.0f;
    for (int q = 0; q < 16; ++q)
      s += LOG2(fmaf(Cj, kmbuf[(c * 16 + q) * 21 + j], 1.0f));
    km2[c][j] = s * LN2;
  }
  __syncthreads();
  if (tid < 21)
    kmv[tid] = fmaxf(km2[0][tid] + km2[1][tid] + km2[2][tid] + km2[3][tid], 0.0f);
  __syncthreads();
  if (tid < 10) {
    float s = b1[tid];
    for (int j = 0; j < 21; ++j) s = fmaf(W1[tid * 21 + j], kmv[j], s);
    x1[tid] = fmaxf(s, 0.0f);
  }
  __syncthreads();
  if (tid < 5) {
    float s = b2[tid];
    for (int i = 0; i < 10; ++i) s = fmaf(W2[tid * 10 + i], x1[i], s);
    x2[tid] = s;
  }
  __syncthreads();
  if (tid == 0) {
    float s = b3[0];
    for (int i = 0; i < 5; ++i) s = fmaf(W3[i], x2[i], s);
    out[b] = s;
  }
}

extern "C" void kernel_launch(void* const* d_in, const int* in_sizes, int n_in,
                              void* d_out, int out_size, void* d_ws, size_t ws_size,
                              hipStream_t stream) {
  const int* query = (const int*)d_in[0];
  const int* doc = (const int*)d_in[1];
  const float* emb = (const float*)d_in[2];
  const float* W1 = (const float*)d_in[3];
  const float* b1 = (const float*)d_in[4];
  const float* W2 = (const float*)d_in[5];
  const float* b2 = (const float*)d_in[6];
  const float* W3 = (const float*)d_in[7];
  const float* b3 = (const float*)d_in[8];
  float* out = (float*)d_out;
  unsigned* embN = (unsigned*)d_ws;  // 50000*64 uints = 12.8 MB bf16 table

  hipLaunchKernelGGL(knrm_norm, dim3(1024), dim3(256), 0, stream, emb, embN);
  hipLaunchKernelGGL(knrm_main, dim3(1024), dim3(256), 0, stream, query, doc, embN,
                     W1, b1, W2, b2, W3, b3, out);
}